// Round 1
// baseline (469.234 us; speedup 1.0000x reference)
//
#include <hip/hip_runtime.h>

// 3D LUT trilinear apply.
// LUT: (3, 33, 33, 33) f32, indexed [channel][blue][green][red]
// x:   (8, 3, 1024, 1024) f32, out: same shape/layout.
// Memory-bound target: ~201 MB HBM => ~32 us at 6.3 TB/s.

namespace {

constexpr int DIM   = 33;
constexpr int WH    = 1024 * 1024;   // 2^20
constexpr int BATCH = 8;
constexpr int NPIX  = BATCH * WH;    // 8388608
constexpr int LUT_C = DIM * DIM * DIM; // 35937

__device__ __forceinline__ void sample_one(
    const float* __restrict__ lut, float r, float g, float b,
    float& outR, float& outG, float& outB)
{
    const float binsize = 1.0001f / (float)(DIM - 1);
    float sr = r / binsize;
    float sg = g / binsize;
    float sb = b / binsize;
    // x in [0,1) => scaled in [0, 31.9968), so plain truncation == floor,
    // idx in [0,31], idx+1 <= 32 always in-bounds.
    int ir = (int)sr, ig = (int)sg, ib = (int)sb;
    float fr = sr - (float)ir;
    float fg = sg - (float)ig;
    float fb = sb - (float)ib;

    int base = ib * (DIM * DIM) + ig * DIM + ir;

    float w00 = (1.f - fg) * (1.f - fb);
    float w10 = fg * (1.f - fb);
    float w01 = (1.f - fg) * fb;
    float w11 = fg * fb;
    float w000 = (1.f - fr) * w00, w100 = fr * w00;
    float w010 = (1.f - fr) * w10, w110 = fr * w10;
    float w001 = (1.f - fr) * w01, w101 = fr * w01;
    float w011 = (1.f - fr) * w11, w111 = fr * w11;

    float res[3];
#pragma unroll
    for (int c = 0; c < 3; ++c) {
        const float* L = lut + c * LUT_C + base;
        res[c] = w000 * L[0]
               + w100 * L[1]
               + w010 * L[DIM]
               + w110 * L[DIM + 1]
               + w001 * L[DIM * DIM]
               + w101 * L[DIM * DIM + 1]
               + w011 * L[DIM * DIM + DIM]
               + w111 * L[DIM * DIM + DIM + 1];
    }
    outR = res[0]; outG = res[1]; outB = res[2];
}

__global__ __launch_bounds__(256) void lut3d_kernel(
    const float* __restrict__ lut, const float* __restrict__ x,
    float* __restrict__ out)
{
    int tid = blockIdx.x * blockDim.x + threadIdx.x;
    int P = tid * 4;                 // 4 pixels per thread
    if (P >= NPIX) return;
    int batch = P >> 20;             // WH == 2^20
    int p = P & (WH - 1);

    const float* xb = x + (size_t)batch * 3 * WH + p;
    float*       ob = out + (size_t)batch * 3 * WH + p;

    float4 r4 = *(const float4*)(xb);
    float4 g4 = *(const float4*)(xb + WH);
    float4 b4 = *(const float4*)(xb + 2 * WH);

    float4 oR, oG, oB;
    sample_one(lut, r4.x, g4.x, b4.x, oR.x, oG.x, oB.x);
    sample_one(lut, r4.y, g4.y, b4.y, oR.y, oG.y, oB.y);
    sample_one(lut, r4.z, g4.z, b4.z, oR.z, oG.z, oB.z);
    sample_one(lut, r4.w, g4.w, b4.w, oR.w, oG.w, oB.w);

    *(float4*)(ob)          = oR;
    *(float4*)(ob + WH)     = oG;
    *(float4*)(ob + 2 * WH) = oB;
}

} // namespace

extern "C" void kernel_launch(void* const* d_in, const int* in_sizes, int n_in,
                              void* d_out, int out_size, void* d_ws, size_t ws_size,
                              hipStream_t stream) {
    const float* lut = (const float*)d_in[0];
    const float* x   = (const float*)d_in[1];
    float*       out = (float*)d_out;

    constexpr int threads_needed = NPIX / 4;      // 2097152
    constexpr int block = 256;
    constexpr int grid  = (threads_needed + block - 1) / block; // 8192
    lut3d_kernel<<<grid, block, 0, stream>>>(lut, x, out);
}

// Round 2
// 307.469 us; speedup vs baseline: 1.5261x; 1.5261x over previous
//
#include <hip/hip_runtime.h>

// 3D LUT trilinear apply — round 2.
// R1 post-mortem: 353 us, HBM 5% / VALU 6% => L1 scatter-address bound
// (24 divergent dword gathers/pixel ~= 1 addr/cy/CU => 327 us predicted, matched).
// Fix: repack LUT (3,33,33,33) SoA -> (33,33,33) float4 AoS in d_ws, so each
// corner is ONE 16B gather (all 3 channels) => 8 gathers/pixel instead of 24.

namespace {

constexpr int DIM    = 33;
constexpr int WH     = 1024 * 1024;     // 2^20
constexpr int BATCH  = 8;
constexpr int NPIX   = BATCH * WH;      // 8388608
constexpr int LUT_N  = DIM * DIM * DIM; // 35937
constexpr size_t WS_NEEDED = (size_t)LUT_N * sizeof(float4); // 574992 B

// ---- prologue: SoA (3,N) -> AoS float4 (N) ----
__global__ __launch_bounds__(256) void repack_kernel(
    const float* __restrict__ lut, float4* __restrict__ ws)
{
    int i = blockIdx.x * blockDim.x + threadIdx.x;
    if (i >= LUT_N) return;
    float4 v;
    v.x = lut[i];
    v.y = lut[LUT_N + i];
    v.z = lut[2 * LUT_N + i];
    v.w = 0.f;
    ws[i] = v;
}

__device__ __forceinline__ void sample_one(
    const float4* __restrict__ lut4, float r, float g, float b,
    float& outR, float& outG, float& outB)
{
    const float inv_binsize = 32.0f / 1.0001f;
    float sr = r * inv_binsize;
    float sg = g * inv_binsize;
    float sb = b * inv_binsize;
    // x in [0,1) => scaled in [0, 31.9968): trunc == floor, idx+1 <= 32 in-bounds.
    int ir = (int)sr, ig = (int)sg, ib = (int)sb;
    float fr = sr - (float)ir;
    float fg = sg - (float)ig;
    float fb = sb - (float)ib;

    int base = ib * (DIM * DIM) + ig * DIM + ir;

    const float4 c000 = lut4[base];
    const float4 c100 = lut4[base + 1];
    const float4 c010 = lut4[base + DIM];
    const float4 c110 = lut4[base + DIM + 1];
    const float4 c001 = lut4[base + DIM * DIM];
    const float4 c101 = lut4[base + DIM * DIM + 1];
    const float4 c011 = lut4[base + DIM * DIM + DIM];
    const float4 c111 = lut4[base + DIM * DIM + DIM + 1];

    float w00 = (1.f - fg) * (1.f - fb);
    float w10 = fg * (1.f - fb);
    float w01 = (1.f - fg) * fb;
    float w11 = fg * fb;
    float w000 = (1.f - fr) * w00, w100 = fr * w00;
    float w010 = (1.f - fr) * w10, w110 = fr * w10;
    float w001 = (1.f - fr) * w01, w101 = fr * w01;
    float w011 = (1.f - fr) * w11, w111 = fr * w11;

    outR = w000 * c000.x + w100 * c100.x + w010 * c010.x + w110 * c110.x
         + w001 * c001.x + w101 * c101.x + w011 * c011.x + w111 * c111.x;
    outG = w000 * c000.y + w100 * c100.y + w010 * c010.y + w110 * c110.y
         + w001 * c001.y + w101 * c101.y + w011 * c011.y + w111 * c111.y;
    outB = w000 * c000.z + w100 * c100.z + w010 * c010.z + w110 * c110.z
         + w001 * c001.z + w101 * c101.z + w011 * c011.z + w111 * c111.z;
}

__global__ __launch_bounds__(256) void lut3d_kernel(
    const float4* __restrict__ lut4, const float* __restrict__ x,
    float* __restrict__ out)
{
    int tid = blockIdx.x * blockDim.x + threadIdx.x;
    int P = tid * 4;                 // 4 pixels per thread
    if (P >= NPIX) return;
    int batch = P >> 20;             // WH == 2^20
    int p = P & (WH - 1);

    const float* xb = x + (size_t)batch * 3 * WH + p;
    float*       ob = out + (size_t)batch * 3 * WH + p;

    float4 r4 = *(const float4*)(xb);
    float4 g4 = *(const float4*)(xb + WH);
    float4 b4 = *(const float4*)(xb + 2 * WH);

    float4 oR, oG, oB;
    sample_one(lut4, r4.x, g4.x, b4.x, oR.x, oG.x, oB.x);
    sample_one(lut4, r4.y, g4.y, b4.y, oR.y, oG.y, oB.y);
    sample_one(lut4, r4.z, g4.z, b4.z, oR.z, oG.z, oB.z);
    sample_one(lut4, r4.w, g4.w, b4.w, oR.w, oG.w, oB.w);

    *(float4*)(ob)          = oR;
    *(float4*)(ob + WH)     = oG;
    *(float4*)(ob + 2 * WH) = oB;
}

// ---- fallback (ws too small): R1 kernel, 24 scalar gathers ----
__device__ __forceinline__ void sample_one_soa(
    const float* __restrict__ lut, float r, float g, float b,
    float& outR, float& outG, float& outB)
{
    const float inv_binsize = 32.0f / 1.0001f;
    float sr = r * inv_binsize, sg = g * inv_binsize, sb = b * inv_binsize;
    int ir = (int)sr, ig = (int)sg, ib = (int)sb;
    float fr = sr - (float)ir, fg = sg - (float)ig, fb = sb - (float)ib;
    int base = ib * (DIM * DIM) + ig * DIM + ir;
    float w00 = (1.f - fg) * (1.f - fb);
    float w10 = fg * (1.f - fb);
    float w01 = (1.f - fg) * fb;
    float w11 = fg * fb;
    float w000 = (1.f - fr) * w00, w100 = fr * w00;
    float w010 = (1.f - fr) * w10, w110 = fr * w10;
    float w001 = (1.f - fr) * w01, w101 = fr * w01;
    float w011 = (1.f - fr) * w11, w111 = fr * w11;
    float res[3];
#pragma unroll
    for (int c = 0; c < 3; ++c) {
        const float* L = lut + c * LUT_N + base;
        res[c] = w000 * L[0] + w100 * L[1] + w010 * L[DIM] + w110 * L[DIM + 1]
               + w001 * L[DIM * DIM] + w101 * L[DIM * DIM + 1]
               + w011 * L[DIM * DIM + DIM] + w111 * L[DIM * DIM + DIM + 1];
    }
    outR = res[0]; outG = res[1]; outB = res[2];
}

__global__ __launch_bounds__(256) void lut3d_kernel_soa(
    const float* __restrict__ lut, const float* __restrict__ x,
    float* __restrict__ out)
{
    int tid = blockIdx.x * blockDim.x + threadIdx.x;
    int P = tid * 4;
    if (P >= NPIX) return;
    int batch = P >> 20;
    int p = P & (WH - 1);
    const float* xb = x + (size_t)batch * 3 * WH + p;
    float*       ob = out + (size_t)batch * 3 * WH + p;
    float4 r4 = *(const float4*)(xb);
    float4 g4 = *(const float4*)(xb + WH);
    float4 b4 = *(const float4*)(xb + 2 * WH);
    float4 oR, oG, oB;
    sample_one_soa(lut, r4.x, g4.x, b4.x, oR.x, oG.x, oB.x);
    sample_one_soa(lut, r4.y, g4.y, b4.y, oR.y, oG.y, oB.y);
    sample_one_soa(lut, r4.z, g4.z, b4.z, oR.z, oG.z, oB.z);
    sample_one_soa(lut, r4.w, g4.w, b4.w, oR.w, oG.w, oB.w);
    *(float4*)(ob)          = oR;
    *(float4*)(ob + WH)     = oG;
    *(float4*)(ob + 2 * WH) = oB;
}

} // namespace

extern "C" void kernel_launch(void* const* d_in, const int* in_sizes, int n_in,
                              void* d_out, int out_size, void* d_ws, size_t ws_size,
                              hipStream_t stream) {
    const float* lut = (const float*)d_in[0];
    const float* x   = (const float*)d_in[1];
    float*       out = (float*)d_out;

    constexpr int threads_needed = NPIX / 4;      // 2097152
    constexpr int block = 256;
    constexpr int grid  = (threads_needed + block - 1) / block; // 8192

    if (ws_size >= WS_NEEDED) {
        float4* lut4 = (float4*)d_ws;
        repack_kernel<<<(LUT_N + 255) / 256, 256, 0, stream>>>(lut, lut4);
        lut3d_kernel<<<grid, block, 0, stream>>>(lut4, x, out);
    } else {
        lut3d_kernel_soa<<<grid, block, 0, stream>>>(lut, x, out);
    }
}

// Round 3
// 223.036 us; speedup vs baseline: 2.1039x; 1.3786x over previous
//
#include <hip/hip_runtime.h>

// 3D LUT trilinear apply — round 3.
// R2 post-mortem: 188 us, L1 scatter-address bound (67M divergent 16B reqs
// ~= 109 us floor + latency). Fix: quantize LUT to 10:10:10 in u32 ->
// 33^3 * 4 B = 143.7 KB, fits gfx950 160 KB LDS. 8 ds_read_b32/pixel with
// imm offsets replaces 8 global float4 gathers. Quant error <= 1/2046 =
// 4.9e-4, threshold is 2e-2 (current absmax 3.9e-3).

namespace {

constexpr int DIM    = 33;
constexpr int WH     = 1024 * 1024;     // 2^20
constexpr int BATCH  = 8;
constexpr int NPIX   = BATCH * WH;      // 8388608
constexpr int LUT_N  = DIM * DIM * DIM; // 35937
constexpr size_t WS_PACKED = (size_t)LUT_N * sizeof(unsigned int); // 143748 B

// ---- prologue: SoA f32 (3,N) -> packed 10:10:10 u32 (N) in d_ws ----
__global__ __launch_bounds__(256) void pack_kernel(
    const float* __restrict__ lut, unsigned int* __restrict__ ws)
{
    int i = blockIdx.x * blockDim.x + threadIdx.x;
    if (i >= LUT_N) return;
    float r = lut[i];
    float g = lut[LUT_N + i];
    float b = lut[2 * LUT_N + i];
    unsigned int qr = (unsigned int)__float2int_rn(__saturatef(r) * 1023.0f);
    unsigned int qg = (unsigned int)__float2int_rn(__saturatef(g) * 1023.0f);
    unsigned int qb = (unsigned int)__float2int_rn(__saturatef(b) * 1023.0f);
    ws[i] = qr | (qg << 10) | (qb << 20);
}

__device__ __forceinline__ void sample_one_lds(
    const unsigned int* __restrict__ lds_lut, float r, float g, float b,
    float& outR, float& outG, float& outB)
{
    const float inv_binsize = 32.0f / 1.0001f;
    float sr = r * inv_binsize;
    float sg = g * inv_binsize;
    float sb = b * inv_binsize;
    // x in [0,1) => scaled in [0, 31.9968): trunc == floor, idx+1 <= 32 in-bounds.
    int ir = (int)sr, ig = (int)sg, ib = (int)sb;
    float fr = sr - (float)ir;
    float fg = sg - (float)ig;
    float fb = sb - (float)ib;

    int base = ib * (DIM * DIM) + ig * DIM + ir;

    // 8 corner fetches: compile-time element offsets 0,1,33,34,1089,1090,1122,1123
    unsigned int p000 = lds_lut[base];
    unsigned int p100 = lds_lut[base + 1];
    unsigned int p010 = lds_lut[base + DIM];
    unsigned int p110 = lds_lut[base + DIM + 1];
    unsigned int p001 = lds_lut[base + DIM * DIM];
    unsigned int p101 = lds_lut[base + DIM * DIM + 1];
    unsigned int p011 = lds_lut[base + DIM * DIM + DIM];
    unsigned int p111 = lds_lut[base + DIM * DIM + DIM + 1];

    float w00 = (1.f - fg) * (1.f - fb);
    float w10 = fg * (1.f - fb);
    float w01 = (1.f - fg) * fb;
    float w11 = fg * fb;
    float w000 = (1.f - fr) * w00, w100 = fr * w00;
    float w010 = (1.f - fr) * w10, w110 = fr * w10;
    float w001 = (1.f - fr) * w01, w101 = fr * w01;
    float w011 = (1.f - fr) * w11, w111 = fr * w11;

    // accumulate raw quantized values; scale once at the end
    float accR, accG, accB;
    accR  = w000 * (float)(p000 & 1023u);
    accG  = w000 * (float)((p000 >> 10) & 1023u);
    accB  = w000 * (float)((p000 >> 20) & 1023u);
    accR += w100 * (float)(p100 & 1023u);
    accG += w100 * (float)((p100 >> 10) & 1023u);
    accB += w100 * (float)((p100 >> 20) & 1023u);
    accR += w010 * (float)(p010 & 1023u);
    accG += w010 * (float)((p010 >> 10) & 1023u);
    accB += w010 * (float)((p010 >> 20) & 1023u);
    accR += w110 * (float)(p110 & 1023u);
    accG += w110 * (float)((p110 >> 10) & 1023u);
    accB += w110 * (float)((p110 >> 20) & 1023u);
    accR += w001 * (float)(p001 & 1023u);
    accG += w001 * (float)((p001 >> 10) & 1023u);
    accB += w001 * (float)((p001 >> 20) & 1023u);
    accR += w101 * (float)(p101 & 1023u);
    accG += w101 * (float)((p101 >> 10) & 1023u);
    accB += w101 * (float)((p101 >> 20) & 1023u);
    accR += w011 * (float)(p011 & 1023u);
    accG += w011 * (float)((p011 >> 10) & 1023u);
    accB += w011 * (float)((p011 >> 20) & 1023u);
    accR += w111 * (float)(p111 & 1023u);
    accG += w111 * (float)((p111 >> 10) & 1023u);
    accB += w111 * (float)((p111 >> 20) & 1023u);

    const float inv1023 = 1.0f / 1023.0f;
    outR = accR * inv1023;
    outG = accG * inv1023;
    outB = accB * inv1023;
}

__global__ __launch_bounds__(1024, 1) void lut3d_lds_kernel(
    const unsigned int* __restrict__ packed, const float* __restrict__ x,
    float* __restrict__ out)
{
    __shared__ unsigned int lds_lut[LUT_N]; // 143748 B

    // cooperative stage: global packed LUT -> LDS
    for (int i = threadIdx.x; i < LUT_N; i += 1024)
        lds_lut[i] = packed[i];
    __syncthreads();

    const int nthreads = gridDim.x * 1024;
    const int ngroups  = NPIX / 4; // float4 pixel groups

    for (int gid = blockIdx.x * 1024 + threadIdx.x; gid < ngroups; gid += nthreads) {
        int P = gid * 4;
        int batch = P >> 20;             // WH == 2^20
        int p = P & (WH - 1);

        const float* xb = x + (size_t)batch * 3 * WH + p;
        float*       ob = out + (size_t)batch * 3 * WH + p;

        float4 r4 = *(const float4*)(xb);
        float4 g4 = *(const float4*)(xb + WH);
        float4 b4 = *(const float4*)(xb + 2 * WH);

        float4 oR, oG, oB;
        sample_one_lds(lds_lut, r4.x, g4.x, b4.x, oR.x, oG.x, oB.x);
        sample_one_lds(lds_lut, r4.y, g4.y, b4.y, oR.y, oG.y, oB.y);
        sample_one_lds(lds_lut, r4.z, g4.z, b4.z, oR.z, oG.z, oB.z);
        sample_one_lds(lds_lut, r4.w, g4.w, b4.w, oR.w, oG.w, oB.w);

        *(float4*)(ob)          = oR;
        *(float4*)(ob + WH)     = oG;
        *(float4*)(ob + 2 * WH) = oB;
    }
}

// ---- fallback (ws too small): R2 float4-gather path ----
__global__ __launch_bounds__(256) void repack_kernel(
    const float* __restrict__ lut, float4* __restrict__ ws)
{
    int i = blockIdx.x * blockDim.x + threadIdx.x;
    if (i >= LUT_N) return;
    float4 v;
    v.x = lut[i];
    v.y = lut[LUT_N + i];
    v.z = lut[2 * LUT_N + i];
    v.w = 0.f;
    ws[i] = v;
}

__device__ __forceinline__ void sample_one_g(
    const float4* __restrict__ lut4, float r, float g, float b,
    float& outR, float& outG, float& outB)
{
    const float inv_binsize = 32.0f / 1.0001f;
    float sr = r * inv_binsize, sg = g * inv_binsize, sb = b * inv_binsize;
    int ir = (int)sr, ig = (int)sg, ib = (int)sb;
    float fr = sr - (float)ir, fg = sg - (float)ig, fb = sb - (float)ib;
    int base = ib * (DIM * DIM) + ig * DIM + ir;
    const float4 c000 = lut4[base];
    const float4 c100 = lut4[base + 1];
    const float4 c010 = lut4[base + DIM];
    const float4 c110 = lut4[base + DIM + 1];
    const float4 c001 = lut4[base + DIM * DIM];
    const float4 c101 = lut4[base + DIM * DIM + 1];
    const float4 c011 = lut4[base + DIM * DIM + DIM];
    const float4 c111 = lut4[base + DIM * DIM + DIM + 1];
    float w00 = (1.f - fg) * (1.f - fb);
    float w10 = fg * (1.f - fb);
    float w01 = (1.f - fg) * fb;
    float w11 = fg * fb;
    float w000 = (1.f - fr) * w00, w100 = fr * w00;
    float w010 = (1.f - fr) * w10, w110 = fr * w10;
    float w001 = (1.f - fr) * w01, w101 = fr * w01;
    float w011 = (1.f - fr) * w11, w111 = fr * w11;
    outR = w000 * c000.x + w100 * c100.x + w010 * c010.x + w110 * c110.x
         + w001 * c001.x + w101 * c101.x + w011 * c011.x + w111 * c111.x;
    outG = w000 * c000.y + w100 * c100.y + w010 * c010.y + w110 * c110.y
         + w001 * c001.y + w101 * c101.y + w011 * c011.y + w111 * c111.y;
    outB = w000 * c000.z + w100 * c100.z + w010 * c010.z + w110 * c110.z
         + w001 * c001.z + w101 * c101.z + w011 * c011.z + w111 * c111.z;
}

__global__ __launch_bounds__(256) void lut3d_kernel_g(
    const float4* __restrict__ lut4, const float* __restrict__ x,
    float* __restrict__ out)
{
    int tid = blockIdx.x * blockDim.x + threadIdx.x;
    int P = tid * 4;
    if (P >= NPIX) return;
    int batch = P >> 20;
    int p = P & (WH - 1);
    const float* xb = x + (size_t)batch * 3 * WH + p;
    float*       ob = out + (size_t)batch * 3 * WH + p;
    float4 r4 = *(const float4*)(xb);
    float4 g4 = *(const float4*)(xb + WH);
    float4 b4 = *(const float4*)(xb + 2 * WH);
    float4 oR, oG, oB;
    sample_one_g(lut4, r4.x, g4.x, b4.x, oR.x, oG.x, oB.x);
    sample_one_g(lut4, r4.y, g4.y, b4.y, oR.y, oG.y, oB.y);
    sample_one_g(lut4, r4.z, g4.z, b4.z, oR.z, oG.z, oB.z);
    sample_one_g(lut4, r4.w, g4.w, b4.w, oR.w, oG.w, oB.w);
    *(float4*)(ob)          = oR;
    *(float4*)(ob + WH)     = oG;
    *(float4*)(ob + 2 * WH) = oB;
}

} // namespace

extern "C" void kernel_launch(void* const* d_in, const int* in_sizes, int n_in,
                              void* d_out, int out_size, void* d_ws, size_t ws_size,
                              hipStream_t stream) {
    const float* lut = (const float*)d_in[0];
    const float* x   = (const float*)d_in[1];
    float*       out = (float*)d_out;

    if (ws_size >= WS_PACKED) {
        unsigned int* packed = (unsigned int*)d_ws;
        pack_kernel<<<(LUT_N + 255) / 256, 256, 0, stream>>>(lut, packed);
        // 256 blocks x 1024 threads, 1 block/CU (LDS-limited), grid-stride.
        lut3d_lds_kernel<<<256, 1024, 0, stream>>>(packed, x, out);
    } else if (ws_size >= (size_t)LUT_N * sizeof(float4)) {
        float4* lut4 = (float4*)d_ws;
        repack_kernel<<<(LUT_N + 255) / 256, 256, 0, stream>>>(lut, lut4);
        constexpr int grid = (NPIX / 4 + 255) / 256;
        lut3d_kernel_g<<<grid, 256, 0, stream>>>(lut4, x, out);
    }
}

// Round 5
// 186.341 us; speedup vs baseline: 2.5182x; 1.1969x over previous
//
#include <hip/hip_runtime.h>

// 3D LUT trilinear apply — round 5 (R4 fix: vector-element reference bind).
// R3 post-mortem: 97 us kernel. LDS gather fixed the L1 bottleneck
// (LDS ~12 us, VALU ~12 us). Limiter: HBM traffic — WRITE_SIZE 265 MiB
// vs 96 MiB output (2.7x write amplification), BW 3.8 TB/s (60% achievable).
// This round: (a) nontemporal loads/stores for the zero-reuse x/out streams,
// (b) software-pipelined grid-stride loop (prefetch next 3x float4),
// (c) LUT quantize folded into per-block LDS fill (drops pack dispatch+d_ws).

namespace {

constexpr int DIM    = 33;
constexpr int WH     = 1024 * 1024;     // 2^20
constexpr int BATCH  = 8;
constexpr int NPIX   = BATCH * WH;      // 8388608
constexpr int LUT_N  = DIM * DIM * DIM; // 35937

constexpr int BLOCKS  = 256;
constexpr int TPB     = 1024;
constexpr int NTHREAD = BLOCKS * TPB;        // 262144
constexpr int NGROUP  = NPIX / 4;            // 2097152 float4-pixel groups
constexpr int NITER   = NGROUP / NTHREAD;    // exactly 8

using f4 = __attribute__((ext_vector_type(4))) float;

__device__ __forceinline__ f4 nt_load4(const float* p) {
    return __builtin_nontemporal_load((const f4*)p);
}
__device__ __forceinline__ void nt_store4(float* p, f4 v) {
    __builtin_nontemporal_store(v, (f4*)p);
}

__device__ __forceinline__ void sample_one_lds(
    const unsigned int* lds_lut, float r, float g, float b,
    float& outR, float& outG, float& outB)
{
    const float inv_binsize = 32.0f / 1.0001f;
    float sr = r * inv_binsize;
    float sg = g * inv_binsize;
    float sb = b * inv_binsize;
    // x in [0,1) => scaled in [0, 31.9968): trunc == floor, idx+1 <= 32 in-bounds.
    int ir = (int)sr, ig = (int)sg, ib = (int)sb;
    float fr = sr - (float)ir;
    float fg = sg - (float)ig;
    float fb = sb - (float)ib;

    int base = ib * (DIM * DIM) + ig * DIM + ir;

    unsigned int p000 = lds_lut[base];
    unsigned int p100 = lds_lut[base + 1];
    unsigned int p010 = lds_lut[base + DIM];
    unsigned int p110 = lds_lut[base + DIM + 1];
    unsigned int p001 = lds_lut[base + DIM * DIM];
    unsigned int p101 = lds_lut[base + DIM * DIM + 1];
    unsigned int p011 = lds_lut[base + DIM * DIM + DIM];
    unsigned int p111 = lds_lut[base + DIM * DIM + DIM + 1];

    float w00 = (1.f - fg) * (1.f - fb);
    float w10 = fg * (1.f - fb);
    float w01 = (1.f - fg) * fb;
    float w11 = fg * fb;
    float w000 = (1.f - fr) * w00, w100 = fr * w00;
    float w010 = (1.f - fr) * w10, w110 = fr * w10;
    float w001 = (1.f - fr) * w01, w101 = fr * w01;
    float w011 = (1.f - fr) * w11, w111 = fr * w11;

    float accR, accG, accB;
    accR  = w000 * (float)(p000 & 1023u);
    accG  = w000 * (float)((p000 >> 10) & 1023u);
    accB  = w000 * (float)((p000 >> 20) & 1023u);
    accR += w100 * (float)(p100 & 1023u);
    accG += w100 * (float)((p100 >> 10) & 1023u);
    accB += w100 * (float)((p100 >> 20) & 1023u);
    accR += w010 * (float)(p010 & 1023u);
    accG += w010 * (float)((p010 >> 10) & 1023u);
    accB += w010 * (float)((p010 >> 20) & 1023u);
    accR += w110 * (float)(p110 & 1023u);
    accG += w110 * (float)((p110 >> 10) & 1023u);
    accB += w110 * (float)((p110 >> 20) & 1023u);
    accR += w001 * (float)(p001 & 1023u);
    accG += w001 * (float)((p001 >> 10) & 1023u);
    accB += w001 * (float)((p001 >> 20) & 1023u);
    accR += w101 * (float)(p101 & 1023u);
    accG += w101 * (float)((p101 >> 10) & 1023u);
    accB += w101 * (float)((p101 >> 20) & 1023u);
    accR += w011 * (float)(p011 & 1023u);
    accG += w011 * (float)((p011 >> 10) & 1023u);
    accB += w011 * (float)((p011 >> 20) & 1023u);
    accR += w111 * (float)(p111 & 1023u);
    accG += w111 * (float)((p111 >> 10) & 1023u);
    accB += w111 * (float)((p111 >> 20) & 1023u);

    const float inv1023 = 1.0f / 1023.0f;
    outR = accR * inv1023;
    outG = accG * inv1023;
    outB = accB * inv1023;
}

__global__ __launch_bounds__(TPB, 1) void lut3d_lds_kernel(
    const float* __restrict__ lut, const float* __restrict__ x,
    float* __restrict__ out)
{
    __shared__ unsigned int lds_lut[LUT_N]; // 143748 B -> 1 block/CU, 16 waves

    // stage: quantize f32 SoA LUT (global, L2/L3-hit) -> 10:10:10 u32 in LDS
    for (int i = threadIdx.x; i < LUT_N; i += TPB) {
        float r = lut[i];
        float g = lut[LUT_N + i];
        float b = lut[2 * LUT_N + i];
        unsigned int qr = (unsigned int)__float2int_rn(__saturatef(r) * 1023.0f);
        unsigned int qg = (unsigned int)__float2int_rn(__saturatef(g) * 1023.0f);
        unsigned int qb = (unsigned int)__float2int_rn(__saturatef(b) * 1023.0f);
        lds_lut[i] = qr | (qg << 10) | (qb << 20);
    }
    __syncthreads();

    int gid = blockIdx.x * TPB + threadIdx.x;

    // prologue load for iteration 0
    int P = gid * 4;
    int batch = P >> 20;
    int p = P & (WH - 1);
    const float* xb = x + (size_t)batch * 3 * WH + p;
    f4 r4 = nt_load4(xb);
    f4 g4 = nt_load4(xb + WH);
    f4 b4 = nt_load4(xb + 2 * WH);

#pragma unroll
    for (int it = 0; it < NITER; ++it) {
        // prefetch next iteration's inputs before the heavy compute
        f4 rn, gn, bn;
        int gnx = gid + NTHREAD;
        if (it + 1 < NITER) {
            int Pn = gnx * 4;
            int bn_ = Pn >> 20;
            int pn  = Pn & (WH - 1);
            const float* xn = x + (size_t)bn_ * 3 * WH + pn;
            rn = nt_load4(xn);
            gn = nt_load4(xn + WH);
            bn = nt_load4(xn + 2 * WH);
        }

        float* ob = out + (size_t)batch * 3 * WH + p;

        f4 oR, oG, oB;
#pragma unroll
        for (int l = 0; l < 4; ++l) {
            float tR, tG, tB;
            sample_one_lds(lds_lut, r4[l], g4[l], b4[l], tR, tG, tB);
            oR[l] = tR; oG[l] = tG; oB[l] = tB;
        }

        nt_store4(ob,          oR);
        nt_store4(ob + WH,     oG);
        nt_store4(ob + 2 * WH, oB);

        // rotate
        gid = gnx;
        P = gid * 4;
        batch = P >> 20;
        p = P & (WH - 1);
        r4 = rn; g4 = gn; b4 = bn;
    }
}

} // namespace

extern "C" void kernel_launch(void* const* d_in, const int* in_sizes, int n_in,
                              void* d_out, int out_size, void* d_ws, size_t ws_size,
                              hipStream_t stream) {
    const float* lut = (const float*)d_in[0];
    const float* x   = (const float*)d_in[1];
    float*       out = (float*)d_out;
    (void)d_ws; (void)ws_size;

    lut3d_lds_kernel<<<BLOCKS, TPB, 0, stream>>>(lut, x, out);
}